// Round 8
// baseline (778.320 us; speedup 1.0000x reference)
//
#include <hip/hip_runtime.h>

#define B_ 4
#define L_ 4096
#define HID_ 1024
#define H_ 16
#define D_ 64
#define DM_ 128
#define CS_ 64
#define NCH_ 64
#define EPS_ 1e-6f

typedef __attribute__((ext_vector_type(8))) short bfrag_t;   // 8 bf16 = 4 VGPRs
typedef __attribute__((ext_vector_type(4))) float facc_t;    // MFMA C/D

#define MFMA16(a,b,c) __builtin_amdgcn_mfma_f32_16x16x32_bf16(a,b,c,0,0,0)

__device__ __forceinline__ float sigf(float x){ return 1.0f/(1.0f + __expf(-x)); }

__device__ __forceinline__ unsigned f2bfu(float x){   // fp32 -> bf16 RNE
  unsigned u = __float_as_uint(x);
  return (u + 0x7fffu + ((u>>16)&1u)) >> 16;
}
__device__ __forceinline__ float bf2f(unsigned short s){
  return __uint_as_float(((unsigned)s)<<16);
}
// packed fp32->bf16 RNE (1 VALU op for 2 values)
__device__ __forceinline__ unsigned cvtpk(float lo, float hi){
  unsigned r;
  asm("v_cvt_pk_bf16_f32 %0, %1, %2" : "=v"(r) : "v"(lo), "v"(hi));
  return r;
}
__device__ __forceinline__ float bflo(unsigned u){ return __uint_as_float(u<<16); }
__device__ __forceinline__ float bfhi(unsigned u){ return __uint_as_float(u & 0xffff0000u); }

// async global->LDS, 16B per lane; LDS dest = wave-uniform base + lane*16
__device__ __forceinline__ void gld16(const unsigned short* g, unsigned short* l){
  __builtin_amdgcn_global_load_lds(
      (const __attribute__((address_space(1))) unsigned int*)(const void*)g,
      (__attribute__((address_space(3))) unsigned int*)(void*)l,
      16, 0, 0);
}

// wave64 sum via DPP row_shr prefix (VALU-speed) + readlane combine.
#define DPP_ADD_(x, ctrl) x += __int_as_float(__builtin_amdgcn_update_dpp(0, __float_as_int(x), ctrl, 0xf, 0xf, true))
__device__ __forceinline__ float wsum64(float x){
  DPP_ADD_(x, 0x111);   // row_shr:1
  DPP_ADD_(x, 0x112);   // row_shr:2
  DPP_ADD_(x, 0x114);   // row_shr:4
  DPP_ADD_(x, 0x118);   // row_shr:8  -> lane 15/31/47/63 hold 16-lane sums
  const float a = __int_as_float(__builtin_amdgcn_readlane(__float_as_int(x), 15));
  const float b = __int_as_float(__builtin_amdgcn_readlane(__float_as_int(x), 31));
  const float c = __int_as_float(__builtin_amdgcn_readlane(__float_as_int(x), 47));
  const float d = __int_as_float(__builtin_amdgcn_readlane(__float_as_int(x), 63));
  return (a+b)+(c+d);
}

// ---------------------------------------------------------------------------
// cast fp32 -> bf16 for x and Wq/Wk/Wv
// ---------------------------------------------------------------------------
__global__ __launch_bounds__(256) void cast_kernel(
    const float* __restrict__ x,  const float* __restrict__ wq,
    const float* __restrict__ wk, const float* __restrict__ wv,
    unsigned short* __restrict__ xb,  unsigned short* __restrict__ wqb,
    unsigned short* __restrict__ wkb, unsigned short* __restrict__ wvb)
{
  const int bid = blockIdx.x;
  const float* s; unsigned short* d; int base;
  if (bid < 16384){ s = x; d = xb; base = bid*1024; }
  else {
    int r = bid - 16384; const int a = r >> 10; r &= 1023; base = r*1024;
    s = (a==0)?wq:(a==1)?wk:wv;
    d = (a==0)?wqb:(a==1)?wkb:wvb;
  }
  const int i = base + threadIdx.x*4;
  float4 v = *(const float4*)(s + i);
  unsigned lo = f2bfu(v.x) | (f2bfu(v.y)<<16);
  unsigned hi = f2bfu(v.z) | (f2bfu(v.w)<<16);
  uint2 o; o.x = lo; o.y = hi;
  *(uint2*)(d + i) = o;
}

// ---------------------------------------------------------------------------
// Fused QKV GEMM: C = A[16384,1024] @ Wcat[3072,1024]^T, 128x128 tile, BK=32.
// 3-buffer global_load_lds pipeline, counted vmcnt(4); LDS-bounce epilogue.
// (round-7 version, measured best)
// ---------------------------------------------------------------------------
#define SC_ 132   // Cs stride (u16); 66 dw == 2 mod 32 -> b16 writes bank-free

__global__ __launch_bounds__(256, 3) void gemm_bf16_nt(
    const unsigned short* __restrict__ A, const unsigned short* __restrict__ Bw,
    unsigned short* __restrict__ C, int M, int N, int K)
{
  // union: staging As[3][4096]+Bs[3][4096] = 48 KB ; epilogue Cs[128][132] = 33 KB
  __shared__ __align__(16) unsigned short smem[24576];
  unsigned short* As = smem;            // [3][4096]
  unsigned short* Bs = smem + 12288;    // [3][4096]

  const int tid = threadIdx.x;
  const int lane = tid & 63, wave = tid >> 6;
  const int lq = lane & 15, quad = lane >> 4;
  const int m0 = blockIdx.y*128, n0 = blockIdx.x*128;
  const int row = tid >> 2, ks = (tid & 3)*8;
  const int mo = (wave & 1)*64, no = (wave >> 1)*64;

  const unsigned short* pa0 = A  + (size_t)(m0 + row)*K + ks;
  const unsigned short* pa1 = pa0 + (size_t)64*K;
  const unsigned short* pb0 = Bw + (size_t)(n0 + row)*K + ks;
  const unsigned short* pb1 = pb0 + (size_t)64*K;

  facc_t acc[4][4];
  #pragma unroll
  for (int i=0;i<4;++i)
    #pragma unroll
    for (int j=0;j<4;++j) acc[i][j] = (facc_t){0.f,0.f,0.f,0.f};

  auto stage = [&](int buf, int kt){
    const int off = kt*32;
    unsigned short* ab = As + buf*4096 + wave*512;
    unsigned short* bb = Bs + buf*4096 + wave*512;
    gld16(pa0 + off, ab);
    gld16(pa1 + off, ab + 2048);
    gld16(pb0 + off, bb);
    gld16(pb1 + off, bb + 2048);
  };

  const int kiters = K >> 5;   // 32
  // prologue: 2 tiles in flight (8 loads); wait oldest 4 -> buf0 ready
  stage(0, 0);
  stage(1, 1);
  asm volatile("s_waitcnt vmcnt(4)" ::: "memory");
  __builtin_amdgcn_s_barrier();
  __builtin_amdgcn_sched_barrier(0);

  int cur = 0;
  for (int kt = 0; kt < kiters; ++kt){
    // issue k+2 stage FIRST (into the buffer all waves finished reading at
    // the barrier ending iteration kt-1)
    if (kt+2 < kiters){
      int b2 = cur + 2; if (b2 >= 3) b2 -= 3;
      stage(b2, kt+2);
    }
    const unsigned short* as = As + cur*4096;
    const unsigned short* bs = Bs + cur*4096;
    bfrag_t af[4], bf[4];
    #pragma unroll
    for (int mt=0;mt<4;++mt) af[mt] = *(const bfrag_t*)&as[(mo+mt*16+lq)*32 + quad*8];
    #pragma unroll
    for (int nt=0;nt<4;++nt) bf[nt] = *(const bfrag_t*)&bs[(no+nt*16+lq)*32 + quad*8];
    #pragma unroll
    for (int mt=0;mt<4;++mt)
      #pragma unroll
      for (int nt=0;nt<4;++nt)
        acc[mt][nt] = MFMA16(af[mt], bf[nt], acc[mt][nt]);
    if (kt+1 < kiters){
      if (kt+2 < kiters) asm volatile("s_waitcnt vmcnt(4)" ::: "memory");
      else               asm volatile("s_waitcnt vmcnt(0)" ::: "memory");
      __builtin_amdgcn_s_barrier();
      __builtin_amdgcn_sched_barrier(0);
    }
    cur = (cur == 2) ? 0 : cur + 1;
  }

  // ---- epilogue: acc -> Cs (LDS) -> coalesced uint4 global stores ----
  __syncthreads();                      // all staging-LDS reads done; reuse smem
  unsigned short* Cs = smem;            // [128][SC_]
  #pragma unroll
  for (int mt=0;mt<4;++mt)
    #pragma unroll
    for (int nt=0;nt<4;++nt)
      #pragma unroll
      for (int r=0;r<4;++r){
        const int lr = mo + mt*16 + quad*4 + r;
        const int lc = no + nt*16 + lq;
        Cs[lr*SC_ + lc] = (unsigned short)f2bfu(acc[mt][nt][r]);
      }
  __syncthreads();
  #pragma unroll
  for (int u=0;u<8;++u){
    const int idx = tid + 256*u;        // 0..2047
    const int ml = idx >> 4, s = idx & 15;
    const int rr = m0 + ml;
    const int cc0 = n0 + s*8;
    const int t = cc0 >> 10, hh = (cc0 >> 6) & 15, dd0 = cc0 & 63;
    const int b = rr >> 12, l = rr & 4095;
    // rows are 264B-strided (8B aligned) -> two b64 LDS reads
    uint2 v0 = *(const uint2*)&Cs[ml*SC_ + s*8];
    uint2 v1 = *(const uint2*)&Cs[ml*SC_ + s*8 + 4];
    uint4 v; v.x = v0.x; v.y = v0.y; v.z = v1.x; v.w = v1.y;
    *(uint4*)&C[((((size_t)t*B_ + b)*H_ + hh)*L_ + l)*64 + dd0] = v;
  }
}

// ---------------------------------------------------------------------------
// Gate logits + per-chunk suffix products. Each block = one (b, chunk).
// NEW this round (only change): inner loop vectorized to float4 LDS reads —
// 7 ds_read_b128 per 4 kk replaces 28 ds_read_b32 (gates is LDS-op-bound).
// ---------------------------------------------------------------------------
__global__ __launch_bounds__(256, 2) void gates_kernel(
  const float* __restrict__ x,
  const float* __restrict__ mdw, const float* __restrict__ mdb,
  const float* __restrict__ sw,  const float* __restrict__ sb,
  const float* __restrict__ lw,  const float* __restrict__ lb,
  float* __restrict__ cmb, float* __restrict__ c1b, float* __restrict__ ppb)
{
  __shared__ float xs[64][68];
  __shared__ float wg[48][68];
  const int tid = threadIdx.x;
  const int m0 = blockIdx.x * 64;
  const int tx = tid & 15, ty = tid >> 4;
  float acc[4][3];
  #pragma unroll
  for (int r=0;r<4;++r){ acc[r][0]=0.f; acc[r][1]=0.f; acc[r][2]=0.f; }

  for (int k0 = 0; k0 < HID_; k0 += 64){
    {
      const int r = tid >> 2, kq = tid & 3;
      const float* xp = x + (size_t)(m0 + r) * HID_ + k0 + kq*16;
      #pragma unroll
      for (int u=0;u<4;++u){
        float4 v = *(const float4*)(xp + u*4);
        *(float4*)&xs[r][kq*16 + u*4] = v;
      }
    }
    #pragma unroll
    for (int u=0;u<3;++u){
      const int idx = tid + 256*u;
      const int gi = idx >> 4, q = idx & 15;
      const float* wp = (gi < 16) ? (mdw + (size_t)gi*HID_)
                      : (gi < 32) ? (sw  + (size_t)(gi-16)*HID_)
                                  : (lw  + (size_t)(gi-32)*HID_);
      float4 v = *(const float4*)(wp + k0 + q*4);
      *(float4*)&wg[gi][q*4] = v;
    }
    __syncthreads();
    #pragma unroll 4
    for (int kk=0; kk<64; kk+=4){
      float4 wv[3];
      #pragma unroll
      for (int gg=0;gg<3;++gg) wv[gg] = *(const float4*)&wg[tx*3+gg][kk];
      #pragma unroll
      for (int r=0;r<4;++r){
        const float4 xv = *(const float4*)&xs[ty*4+r][kk];
        #pragma unroll
        for (int gg=0;gg<3;++gg)
          acc[r][gg] += xv.x*wv[gg].x + xv.y*wv[gg].y + xv.z*wv[gg].z + xv.w*wv[gg].w;
      }
    }
    __syncthreads();
  }

  float (*ls)[68] = xs;
  #pragma unroll
  for (int gg=0; gg<3; ++gg){
    const int gi = tx*3 + gg;
    const int s = gi >> 4, hh = gi & 15;
    const float bias = (s==0) ? mdb[hh] : (s==1) ? sb[hh] : lb[hh];
    #pragma unroll
    for (int r=0;r<4;++r) ls[gi][ty*4+r] = acc[r][gg] + bias;
  }
  __syncthreads();

  const int lane = tid & 63, wv2 = tid >> 6;
  const int b = m0 >> 12, n = (m0 & 4095) >> 6;
  #pragma unroll
  for (int u=0;u<4;++u){
    const int hh = wv2*4 + u;
    const float md = 1.0f - sigf(ls[hh][lane]);
    const float sd = sigf(ls[16+hh][lane]);
    const float lr = sigf(ls[32+hh][lane]);
    float vm = md, vs = sd;
    #pragma unroll
    for (int off = 1; off < 64; off <<= 1){
      float om = __shfl_down(vm, off);
      float os = __shfl_down(vs, off);
      if (lane + off < 64){ vm *= om; vs *= os; }
    }
    float mex = __shfl_down(vm, 1);
    float sex = __shfl_down(vs, 1);
    if (lane == 63){ mex = 1.0f; sex = 1.0f; }
    const size_t base = ((size_t)(b*16 + hh)*NCH_ + n)*64;
    cmb[base + lane] = mex;
    c1b[base + lane] = -lr * sex;
    if (lane == 0){
      ppb[((size_t)(b*16+hh)*NCH_ + n)*2 + 0] = vm;
      ppb[((size_t)(b*16+hh)*NCH_ + n)*2 + 1] = vs;
    }
  }
}

// ---------------------------------------------------------------------------
// halo_kernel: snapshot RAW q/k/v rows (ch*64-3 .. ch*64-1) before prep
// overwrites them in place. halo layout: [tensor][bh][ch][3][64] bf16.
// ---------------------------------------------------------------------------
#define HALO_T_ ((size_t)64*64*3*64)

__global__ __launch_bounds__(192) void halo_kernel(
  const unsigned short* __restrict__ qg, const unsigned short* __restrict__ kg,
  const unsigned short* __restrict__ vg, unsigned short* __restrict__ halo)
{
  const int blk = blockIdx.x;          // 64*63 blocks
  const int bh = blk / 63;
  const int ch = blk % 63 + 1;         // 1..63
  const int tid = threadIdx.x;
  const int tt = tid >> 6, lane = tid & 63;
  const long src = ((long)bh*L_ + (long)ch*64 - 3 + tt)*64 + lane;
  const long dst = (((long)bh*64 + ch)*3 + tt)*64 + lane;
  halo[dst]               = qg[src];
  halo[dst +   HALO_T_]   = kg[src];
  halo[dst + 2*HALO_T_]   = vg[src];
}

// ---------------------------------------------------------------------------
// prep_kernel: conv+silu(+rmsnorm for q,k) IN PLACE over gemm output, plus
// kred[bh][ch][d] = sum_i cm[i]*kc_bf16[i][d]. One block per (bh, chunk).
// ---------------------------------------------------------------------------
__global__ __launch_bounds__(256) void prep_kernel(
  unsigned short* __restrict__ qg, unsigned short* __restrict__ kg,
  unsigned short* __restrict__ vg,
  const unsigned short* __restrict__ halo,
  const float* __restrict__ cmg,
  const float* __restrict__ cqw, const float* __restrict__ cqb,
  const float* __restrict__ ckw, const float* __restrict__ ckb,
  const float* __restrict__ cvw, const float* __restrict__ cvb,
  const float* __restrict__ qnw, const float* __restrict__ knw,
  float* __restrict__ kredg)
{
  const int blk = blockIdx.x;          // bh*64 + ch
  const int bh = blk >> 6, ch = blk & 63;
  const int tid = threadIdx.x;
  const int lane = tid & 63, wave = tid >> 6;
  const int h = bh & 15;
  const int c = h*64 + lane;

  float wq4[4], wk4[4], wv4[4];
  #pragma unroll
  for (int kk=0;kk<4;++kk){ wq4[kk]=cqw[c*4+kk]; wk4[kk]=ckw[c*4+kk]; wv4[kk]=cvw[c*4+kk]; }
  const float bq = cqb[c], bk = ckb[c], bv = cvb[c];
  const float qnf = qnw[lane], knf = knw[lane];

  const long base = ((long)bh*L_ + (long)ch*64)*64 + lane;
  const int r0 = wave*16;

  // ---- sliding window init (RAW values, read before any in-block write) ----
  float qw_[3], kw_[3], vw_[3];
  #pragma unroll
  for (int t=0;t<3;++t){
    const int row = r0 - 3 + t;
    if (row >= 0){
      qw_[t] = bf2f(qg[base + (long)row*64]);
      kw_[t] = bf2f(kg[base + (long)row*64]);
      vw_[t] = bf2f(vg[base + (long)row*64]);
    } else if (ch == 0){
      qw_[t] = 0.f; kw_[t] = 0.f; vw_[t] = 0.f;
    } else {
      const long hb = (((long)bh*64 + ch)*3 + (row + 3))*64 + lane;
      qw_[t] = bf2f(halo[hb]);
      kw_[t] = bf2f(halo[hb +   HALO_T_]);
      vw_[t] = bf2f(halo[hb + 2*HALO_T_]);
    }
  }
  __syncthreads();   // all cross-wave RAW reads done before any write

  const float* cmp = cmg + ((size_t)bh*NCH_ + ch)*64;
  float kp = 0.f;
  #pragma unroll 8
  for (int i=0;i<16;++i){
    const int row = r0 + i;
    const long a = base + (long)row*64;
    const float q0v = bf2f(qg[a]);
    const float k0v = bf2f(kg[a]);
    const float v0v = bf2f(vg[a]);
    float aq = bq + wq4[0]*qw_[0] + wq4[1]*qw_[1] + wq4[2]*qw_[2] + wq4[3]*q0v;
    float ak = bk + wk4[0]*kw_[0] + wk4[1]*kw_[1] + wk4[2]*kw_[2] + wk4[3]*k0v;
    float av = bv + wv4[0]*vw_[0] + wv4[1]*vw_[1] + wv4[2]*vw_[2] + wv4[3]*v0v;
    const float yk = ak*sigf(ak), yq = aq*sigf(aq), yv = av*sigf(av);
    const float ssk = wsum64(yk*yk);
    const float ssq = wsum64(yq*yq);
    const float vk = knf * yk * rsqrtf(ssk*(1.0f/64.0f) + EPS_);
    const float vq = qnf * yq * rsqrtf(ssq*(1.0f/64.0f) + EPS_);
    const unsigned short kb16 = (unsigned short)f2bfu(vk);
    qg[a] = (unsigned short)f2bfu(vq);
    kg[a] = kb16;
    vg[a] = (unsigned short)f2bfu(yv);
    kp += cmp[row] * bf2f(kb16);
    qw_[0]=qw_[1]; qw_[1]=qw_[2]; qw_[2]=q0v;
    kw_[0]=kw_[1]; kw_[1]=kw_[2]; kw_[2]=k0v;
    vw_[0]=vw_[1]; vw_[1]=vw_[2]; vw_[2]=v0v;
  }

  __shared__ float kpart[4][64];
  kpart[wave][lane] = kp;
  __syncthreads();
  if (wave == 0)
    kredg[((size_t)bh*NCH_ + ch)*64 + lane] =
        (kpart[0][lane]+kpart[1][lane]) + (kpart[2][lane]+kpart[3][lane]);
}

// ---------------------------------------------------------------------------
// MFMA chunk scan: 1024 threads (16 waves), round-2 6-barrier schedule
// (best measured: 399 us; P8-swap/sgk variants regressed).
// ---------------------------------------------------------------------------
#define SK 72    // stride (u16) of 64-wide arrays  (36 dw == 4 mod 32)
#define SX 136   // stride (u16) of 128-wide arrays (68 dw == 4 mod 32)

__global__ __launch_bounds__(1024, 4) void scan_kernel(
  const unsigned short* __restrict__ qg, const unsigned short* __restrict__ kg,
  const unsigned short* __restrict__ vg,
  const float* __restrict__ cmg, const float* __restrict__ c1g,
  const float* __restrict__ ppg, const float* __restrict__ krg,
  const float* __restrict__ W1in, const float* __restrict__ W2in,
  float* __restrict__ out)
{
  const int bh = blockIdx.x;
  const int h = bh & 15;
  const int tid = threadIdx.x;
  const int lane = tid & 63, wave = tid >> 6;      // wave 0..15
  const int lq = lane & 15, quad = lane >> 4;
  const int wg = wave & 3;                         // row group 0..3
  const int rw = wg * 16;
  const int cw = wave >> 2;                        // col group 0..3
  const int r0 = rw + quad*4;

  // u16 offsets: kcs s: s*4608; qcs: 9216+s*4608; gms: 18432+s*4608;
  // xbs: 27648; W1T: 36352; W2n: 45568; W2T: 54784; end 63488 (127 KB)
  __shared__ __align__(16) unsigned short sm[63488];
  unsigned short* xbs = sm + 27648;   // [64][SX]
  unsigned short* W1T = sm + 36352;   // [128][SK]  W1^T (k=d contiguous)
  unsigned short* W2n = sm + 45568;   // [128][SK]  W2 [j][e]
  unsigned short* W2T = sm + 54784;   // [64][SX]   W2^T [e][j]
  __shared__ float cmA[2][64], c1A[2][64], krA[2][64], ppS[2][2];
  __shared__ float kmomS[64], xmomS[128], w1momS[128], w2momS[64];
  __shared__ float xpart[4][128], w1part[4][128], w2part[4][64];

  // ---- init state: each thread one 8-elem strip ----
  {
    const int j = tid >> 3, q0 = (tid & 7) * 8;
    const float* w1p = W1in + (size_t)h * D_ * DM_;
    #pragma unroll
    for (int t=0;t<8;++t)
      W1T[j*SK + q0 + t] = (unsigned short)f2bfu(w1p[(size_t)(q0+t)*DM_ + j]);
    const float* w2p = W2in + (size_t)h * DM_ * D_ + (size_t)j*D_ + q0;
    #pragma unroll
    for (int t=0;t<8;++t){
      unsigned short v = (unsigned short)f2bfu(w2p[t]);
      W2n[j*SK + q0 + t] = v;
      W2T[(q0+t)*SX + j] = v;
    }
  }
  if (tid < 64){ kmomS[tid]=0.f; w2momS[tid]=0.f; }
  if (tid < 128){ xmomS[tid]=0.f; w1momS[tid]=0.f; }

  const long cbase = (long)bh * L_ * 64;   // head-major
  const int tr = tid >> 4, tc = (tid & 15) * 4;   // 64 rows x 64 cols, uint2

  uint2 rq2, rk2, rv2;
  float cmr=0.f, c1r=0.f, krr=0.f, ppr=0.f;

  auto stage_load = [&](int m){
    if (m >= NCH_) return;
    const long a = cbase + ((long)m*64 + tr)*64 + tc;
    rq2 = *(const uint2*)(qg + a);
    rk2 = *(const uint2*)(kg + a);
    rv2 = *(const uint2*)(vg + a);
    if (wave == 0){
      cmr = cmg[((size_t)bh*NCH_ + m)*64 + lane];
      c1r = c1g[((size_t)bh*NCH_ + m)*64 + lane];
      krr = krg[((size_t)bh*NCH_ + m)*64 + lane];
    }
    if (tid < 2) ppr = ppg[((size_t)bh*NCH_ + m)*2 + tid];
  };

  auto stage_store = [&](int m, int s){
    if (m >= NCH_) return;
    unsigned short* kc = sm + s*4608;
    unsigned short* qc = sm + 9216 + s*4608;
    unsigned short* gm = sm + 18432 + s*4608;
    *(uint2*)&kc[tr*SK + tc] = rk2;
    *(uint2*)&qc[tr*SK + tc] = rq2;
    *(uint2*)&gm[tr*SK + tc] = rv2;
    if (wave == 0){ cmA[s][lane] = cmr; c1A[s][lane] = c1r; krA[s][lane] = krr; }
    if (tid < 2) ppS[s][tid] = ppr;
  };

  stage_load(0);
  stage_store(0, 0);
  __syncthreads();

  for (int n = 0; n < NCH_; ++n){
    const int cur = n & 1, nxt = cur ^ 1;
    const unsigned short* kcs = sm + cur*4608;
    const unsigned short* qcs = sm + 9216 + cur*4608;
    unsigned short* gms = sm + 18432 + cur*4608;

    stage_load(n+1);   // global loads issue here; latency hides under P2/P4

    // ---- P2: Z1 = kc @ W1 ; X1 = silu(Z1) -> xbs ; xmom partials ----
    facc_t zk[2];
    {
      const bfrag_t a0 = *(const bfrag_t*)&kcs[(rw+lq)*SK + quad*8];
      const bfrag_t a1 = *(const bfrag_t*)&kcs[(rw+lq)*SK + 32 + quad*8];
      const float4 cmv = *(const float4*)&cmA[cur][r0];
      #pragma unroll
      for (int nt=0;nt<2;++nt){
        const int j = cw*32 + nt*16 + lq;
        const bfrag_t b0 = *(const bfrag_t*)&W1T[j*SK + quad*8];
        const bfrag_t b1 = *(const bfrag_t*)&W1T[j*SK + 32 + quad*8];
        facc_t z = {0.f,0.f,0.f,0.f};
        z = MFMA16(a0,b0,z); z = MFMA16(a1,b1,z);
        zk[nt] = z;
        const float x0 = z[0]*sigf(z[0]), x1 = z[1]*sigf(z[1]);
        const float x2 = z[2]*sigf(z[2]), x3 = z[3]*sigf(z[3]);
        const unsigned p01 = cvtpk(x0,x1), p23 = cvtpk(x2,x3);
        xbs[(r0+0)*SX + j] = (unsigned short)p01;
        xbs[(r0+1)*SX + j] = (unsigned short)(p01>>16);
        xbs[(r0+2)*SX + j] = (unsigned short)p23;
        xbs[(r0+3)*SX + j] = (unsigned short)(p23>>16);
        float xp = cmv.x*x0 + cmv.y*x1 + cmv.z*x2 + cmv.w*x3;
        xp += __shfl_xor(xp, 16);
        xp += __shfl_xor(xp, 32);
        if (quad == 0) xpart[wg][j] = xp;
      }
    }
    __syncthreads();   // b1

    // ---- P4: g_m = X1 @ W2 - v ; w2mom partial ; kmom/xmom finalize ----
    {
      bfrag_t xa[4];
      #pragma unroll
      for (int kt=0;kt<4;++kt) xa[kt] = *(const bfrag_t*)&xbs[(rw+lq)*SX + kt*32 + quad*8];
      const int e = cw*16 + lq;
      facc_t z = {0.f,0.f,0.f,0.f};
      #pragma unroll
      for (int kt=0;kt<4;++kt){
        const bfrag_t bb = *(const bfrag_t*)&W2T[e*SX + kt*32 + quad*8];
        z = MFMA16(xa[kt], bb, z);
      }
      const float g0 = z[0] - bf2f(gms[(r0+0)*SK + e]);
      const float g1 = z[1] - bf2f(gms[(r0+1)*SK + e]);
      const float g2 = z[2] - bf2f(gms[(r0+2)*SK + e]);
      const float g3 = z[3] - bf2f(gms[(r0+3)*SK + e]);
      const unsigned p01 = cvtpk(g0,g1), p23 = cvtpk(g2,g3);
      gms[(r0+0)*SK + e] = (unsigned short)p01;
      gms[(r0+1)*SK + e] = (unsigned short)(p01>>16);
      gms[(r0+2)*SK + e] = (unsigned short)p23;
      gms[(r0+3)*SK + e] = (unsigned short)(p23>>16);
      const float4 c1v = *(const float4*)&c1A[cur][r0];
      float wp = c1v.x*g0 + c1v.y*g1 + c1v.z*g2 + c1v.w*g3;
      wp += __shfl_xor(wp, 16);
      wp += __shfl_xor(wp, 32);
      if (quad == 0) w2part[wg][e] = wp;
    }
    if (tid < 64) kmomS[tid] = ppS[cur][0]*kmomS[tid] + krA[cur][tid];
    if (tid < 128)
      xmomS[tid] = ppS[cur][0]*xmomS[tid]
                 + ((xpart[0][tid]+xpart[1][tid])+(xpart[2][tid]+xpart[3][tid]));
    stage_store(n+1, nxt);
    __syncthreads();   // b2

    // ---- P5: gZ1 -> xbs ; w1mom partial ; w2mom finalize ----
    {
      const bfrag_t a0 = *(const bfrag_t*)&gms[(rw+lq)*SK + quad*8];
      const bfrag_t a1 = *(const bfrag_t*)&gms[(rw+lq)*SK + 32 + quad*8];
      const float4 c1v = *(const float4*)&c1A[cur][r0];
      #pragma unroll
      for (int nt=0;nt<2;++nt){
        const int j = cw*32 + nt*16 + lq;
        const bfrag_t b0 = *(const bfrag_t*)&W2n[j*SK + quad*8];
        const bfrag_t b1 = *(const bfrag_t*)&W2n[j*SK + 32 + quad*8];
        facc_t gz = {0.f,0.f,0.f,0.f};
        gz = MFMA16(a0,b0,gz); gz = MFMA16(a1,b1,gz);
        float d[4];
        #pragma unroll
        for (int r=0;r<4;++r){
          const float zz = zk[nt][r];
          const float sg = sigf(zz);
          d[r] = gz[r] * (sg * (1.0f + zz*(1.0f - sg)));
        }
        const unsigned p01 = cvtpk(d[0],d[1]), p23 = cvtpk(d[2],d[3]);
        xbs[(r0+0)*SX + j] = (unsigned short)p01;
        xbs[(r0+1)*SX + j] = (unsigned short)(p01>>16);
        xbs[(r0+2)*SX + j] = (unsigned short)p23;
        xbs[(r0+3)*SX + j] = (unsigned short)(p23>>16);
        float wp = c1v.x*d[0] + c1v.y*d[1] + c1v.z*d[2] + c1v.w*d[3];
        wp += __shfl_xor(wp, 16);
        wp += __shfl_xor(wp, 32);
        if (quad == 0) w1part[wg][j] = wp;
      }
    }
    if (tid < 64)
      w2momS[tid] = ppS[cur][1]*w2momS[tid]
                  + ((w2part[0][tid]+w2part[1][tid])+(w2part[2][tid]+w2part[3][tid]));
    __syncthreads();   // b3

    // ---- P7: w1mom finalize (inline, same-wave lockstep) + rank-1 updates ----
    {
      const float Pmd = ppS[cur][0], Psd = ppS[cur][1];
      const int j = tid >> 3, q0 = (tid & 7)*8;
      const float w1m = Psd*w1momS[j]
          + ((w1part[0][j]+w1part[1][j])+(w1part[2][j]+w1part[3][j]));
      if ((tid & 7) == 0) w1momS[j] = w1m;   // 8 threads/j share one wave
      const float xm = xmomS[j];
      const float4 km0 = *(const float4*)&kmomS[q0];
      const float4 km1 = *(const float4*)&kmomS[q0+4];
      {
        const int off = j*SK + q0;
        const uint4 w = *(const uint4*)&W1T[off];
        uint4 o;
        o.x = cvtpk(Pmd*bflo(w.x) + w1m*km0.x, Pmd*bfhi(w.x) + w1m*km0.y);
        o.y = cvtpk(Pmd*bflo(w.y) + w1m*km0.z, Pmd*bfhi(w.y) + w1m*km0.w);
        o.z = cvtpk(Pmd*bflo(w.z) + w1m*km1.x, Pmd*bfhi(w.z) + w1m*km1.y);
        o.w = cvtpk(Pmd*bflo(w.w) + w1m*km1.z, Pmd*bfhi(w.w) + w1m*km1.w);
        *(uint4*)&W1T[off] = o;
      }
      const float4 wm0 = *(const float4*)&w2momS[q0];
      const float4 wm1 = *(const float4*)&w2momS[q0+4];
      {
        const int off = j*SK + q0;
        const uint4 w = *(const uint4*)&W2n[off];
        uint4 o;
        o.x = cvtpk(Pmd*bflo(w.x) + xm*wm0.x, Pmd*bfhi(w.x) + xm*wm0.y);
        o.y = cvtpk(Pmd*bflo(w.y) + xm*wm0.z, Pmd*bfhi(w.y) + xm*wm0.w);
        o.z = cvtpk(Pmd*bflo(w.z) + xm*wm1.x, Pmd*bfhi(w.z) + xm*wm1.y);
        o.w = cvtpk(Pmd*bflo(w.w) + xm*wm1.z, Pmd*bfhi(w.w) + xm*wm1.w);
        *(uint4*)&W2n[off] = o;
      }
      const int e2 = tid >> 4, js = (tid & 15)*8;
      const float w2m = w2momS[e2];
      const float4 xm0 = *(const float4*)&xmomS[js];
      const float4 xm1 = *(const float4*)&xmomS[js+4];
      {
        const int off = e2*SX + js;
        const uint4 w = *(const uint4*)&W2T[off];
        uint4 o;
        o.x = cvtpk(Pmd*bflo(w.x) + xm0.x*w2m, Pmd*bfhi(w.x) + xm0.y*w2m);
        o.y = cvtpk(Pmd*bflo(w.y) + xm0.z*w2m, Pmd*bfhi(w.y) + xm0.w*w2m);
        o.z = cvtpk(Pmd*bflo(w.z) + xm1.x*w2m, Pmd*bfhi(w.z) + xm1.y*w2m);
        o.w = cvtpk(Pmd*bflo(w.w) + xm1.z*w2m, Pmd*bfhi(w.w) + xm1.w*w2m);
        *(uint4*)&W2T[off] = o;
      }
    }
    __syncthreads();   // b4

    // ---- P8: hq = silu(qc @ W1new) -> xbs ----
    {
      const bfrag_t a0 = *(const bfrag_t*)&qcs[(rw+lq)*SK + quad*8];
      const bfrag_t a1 = *(const bfrag_t*)&qcs[(rw+lq)*SK + 32 + quad*8];
      #pragma unroll
      for (int nt=0;nt<2;++nt){
        const int j = cw*32 + nt*16 + lq;
        const bfrag_t b0 = *(const bfrag_t*)&W1T[j*SK + quad*8];
        const bfrag_t b1 = *(const bfrag_t*)&W1T[j*SK + 32 + quad*8];
        facc_t z = {0.f,0.f,0.f,0.f};
        z = MFMA16(a0,b0,z); z = MFMA16(a1,b1,z);
        const float x0 = z[0]*sigf(z[0]), x1 = z[1]*sigf(z[1]);
        const float x2 = z[2]*sigf(z[2]), x3 = z[3]*sigf(z[3]);
        const unsigned p01 = cvtpk(x0,x1), p23 = cvtpk(x2,x3);
        xbs[(r0+0)*SX + j] = (unsigned short)p01;
        xbs[(r0+1)*SX + j] = (unsigned short)(p01>>16);
        xbs[(r0+2)*SX + j] = (unsigned short)p23;
        xbs[(r0+3)*SX + j] = (unsigned short)(p23>>16);
      }
    }
    __syncthreads();   // b5

    // ---- P9: y = hq @ W2new -> out (B,H,D,L flat) ----
    {
      bfrag_t xa[4];
      #pragma unroll
      for (int kt=0;kt<4;++kt) xa[kt] = *(const bfrag_t*)&xbs[(rw+lq)*SX + kt*32 + quad*8];
      const int e = cw*16 + lq;
      facc_t y = {0.f,0.f,0.f,0.f};
      #pragma unroll
      for (int kt=0;kt<4;++kt){
        const bfrag_t bb = *(const bfrag_t*)&W2T[e*SX + kt*32 + quad*8];
        y = MFMA16(xa[kt], bb, y);
      }
      float4 ov; ov.x = y[0]; ov.y = y[1]; ov.z = y[2]; ov.w = y[3];
      *(float4*)&out[(size_t)bh*D_*L_ + (size_t)e*L_ + n*64 + rw + quad*4] = ov;
    }
    __syncthreads();   // b6
  }
}

extern "C" void kernel_launch(void* const* d_in, const int* in_sizes, int n_in,
                              void* d_out, int out_size, void* d_ws, size_t ws_size,
                              hipStream_t stream)
{
  const float* x   = (const float*)d_in[0];
  const float* Wq  = (const float*)d_in[1];
  const float* Wk  = (const float*)d_in[2];
  const float* Wv  = (const float*)d_in[3];
  const float* cqw = (const float*)d_in[4];
  const float* cqb = (const float*)d_in[5];
  const float* ckw = (const float*)d_in[6];
  const float* ckb = (const float*)d_in[7];
  const float* cvw = (const float*)d_in[8];
  const float* cvb = (const float*)d_in[9];
  const float* qnw = (const float*)d_in[10];
  const float* knw = (const float*)d_in[11];
  const float* mdw = (const float*)d_in[12];
  const float* mdb = (const float*)d_in[13];
  const float* sw  = (const float*)d_in[14];
  const float* sb  = (const float*)d_in[15];
  const float* lw  = (const float*)d_in[16];
  const float* lb  = (const float*)d_in[17];
  const float* W1  = (const float*)d_in[18];
  const float* W2  = (const float*)d_in[19];
  float* out = (float*)d_out;

  const size_t SZ  = (size_t)B_ * L_ * HID_;   // 16,777,216
  const size_t WSZ = (size_t)HID_ * HID_;      //  1,048,576
  unsigned short* xb  = (unsigned short*)d_ws;
  unsigned short* wqb = xb  + SZ;      // wq/wk/wv contiguous = Wcat[3072][1024]
  unsigned short* wkb = wqb + WSZ;
  unsigned short* wvb = wkb + WSZ;
  unsigned short* qb  = wvb + WSZ;     // q/k/v contiguous, head-major each
  unsigned short* kb  = qb  + SZ;
  unsigned short* vb  = kb  + SZ;
  float* cmb = (float*)(vb + SZ);
  float* c1b = cmb + (size_t)B_*H_*NCH_*64;
  float* ppb = c1b + (size_t)B_*H_*NCH_*64;
  float* kredg = ppb + (size_t)B_*H_*NCH_*2;
  unsigned short* halo = (unsigned short*)(kredg + (size_t)B_*H_*NCH_*64);

  cast_kernel<<<16384 + 3*1024, 256, 0, stream>>>(x, Wq, Wk, Wv, xb, wqb, wkb, wvb);
  dim3 gg(3*HID_/128, (B_*L_)/128);
  gemm_bf16_nt<<<gg, 256, 0, stream>>>(xb, wqb, qb, B_*L_, 3*HID_, HID_);
  gates_kernel<<<(B_*L_)/64, 256, 0, stream>>>(x, mdw, mdb, sw, sb, lw, lb, cmb, c1b, ppb);
  halo_kernel<<<64*63, 192, 0, stream>>>(qb, kb, vb, halo);
  prep_kernel<<<B_*H_*NCH_, 256, 0, stream>>>(qb, kb, vb, halo, cmb,
                                              cqw, cqb, ckw, ckb, cvw, cvb,
                                              qnw, knw, kredg);
  scan_kernel<<<B_*H_, 1024, 0, stream>>>(qb, kb, vb, cmb, c1b, ppb, kredg,
                                          W1, W2, out);
}

// Round 10
// 758.930 us; speedup vs baseline: 1.0255x; 1.0255x over previous
//
#include <hip/hip_runtime.h>

#define B_ 4
#define L_ 4096
#define HID_ 1024
#define H_ 16
#define D_ 64
#define DM_ 128
#define CS_ 64
#define NCH_ 64
#define EPS_ 1e-6f

typedef __attribute__((ext_vector_type(8))) short bfrag_t;   // 8 bf16 = 4 VGPRs
typedef __attribute__((ext_vector_type(4))) float facc_t;    // MFMA C/D

#define MFMA16(a,b,c) __builtin_amdgcn_mfma_f32_16x16x32_bf16(a,b,c,0,0,0)

__device__ __forceinline__ float sigf(float x){ return 1.0f/(1.0f + __expf(-x)); }

__device__ __forceinline__ unsigned f2bfu(float x){   // fp32 -> bf16 RNE
  unsigned u = __float_as_uint(x);
  return (u + 0x7fffu + ((u>>16)&1u)) >> 16;
}
__device__ __forceinline__ float bf2f(unsigned short s){
  return __uint_as_float(((unsigned)s)<<16);
}
// packed fp32->bf16 RNE (1 VALU op for 2 values)
__device__ __forceinline__ unsigned cvtpk(float lo, float hi){
  unsigned r;
  asm("v_cvt_pk_bf16_f32 %0, %1, %2" : "=v"(r) : "v"(lo), "v"(hi));
  return r;
}
__device__ __forceinline__ float bflo(unsigned u){ return __uint_as_float(u<<16); }
__device__ __forceinline__ float bfhi(unsigned u){ return __uint_as_float(u & 0xffff0000u); }

// async global->LDS, 16B per lane; LDS dest = wave-uniform base + lane*16
__device__ __forceinline__ void gld16(const unsigned short* g, unsigned short* l){
  __builtin_amdgcn_global_load_lds(
      (const __attribute__((address_space(1))) unsigned int*)(const void*)g,
      (__attribute__((address_space(3))) unsigned int*)(void*)l,
      16, 0, 0);
}

// wave64 sum via DPP row_shr prefix (VALU-speed) + readlane combine.
#define DPP_ADD_(x, ctrl) x += __int_as_float(__builtin_amdgcn_update_dpp(0, __float_as_int(x), ctrl, 0xf, 0xf, true))
__device__ __forceinline__ float wsum64(float x){
  DPP_ADD_(x, 0x111);   // row_shr:1
  DPP_ADD_(x, 0x112);   // row_shr:2
  DPP_ADD_(x, 0x114);   // row_shr:4
  DPP_ADD_(x, 0x118);   // row_shr:8  -> lane 15/31/47/63 hold 16-lane sums
  const float a = __int_as_float(__builtin_amdgcn_readlane(__float_as_int(x), 15));
  const float b = __int_as_float(__builtin_amdgcn_readlane(__float_as_int(x), 31));
  const float c = __int_as_float(__builtin_amdgcn_readlane(__float_as_int(x), 47));
  const float d = __int_as_float(__builtin_amdgcn_readlane(__float_as_int(x), 63));
  return (a+b)+(c+d);
}

// ---------------------------------------------------------------------------
// cast fp32 -> bf16 for x and Wq/Wk/Wv
// ---------------------------------------------------------------------------
__global__ __launch_bounds__(256) void cast_kernel(
    const float* __restrict__ x,  const float* __restrict__ wq,
    const float* __restrict__ wk, const float* __restrict__ wv,
    unsigned short* __restrict__ xb,  unsigned short* __restrict__ wqb,
    unsigned short* __restrict__ wkb, unsigned short* __restrict__ wvb)
{
  const int bid = blockIdx.x;
  const float* s; unsigned short* d; int base;
  if (bid < 16384){ s = x; d = xb; base = bid*1024; }
  else {
    int r = bid - 16384; const int a = r >> 10; r &= 1023; base = r*1024;
    s = (a==0)?wq:(a==1)?wk:wv;
    d = (a==0)?wqb:(a==1)?wkb:wvb;
  }
  const int i = base + threadIdx.x*4;
  float4 v = *(const float4*)(s + i);
  unsigned lo = f2bfu(v.x) | (f2bfu(v.y)<<16);
  unsigned hi = f2bfu(v.z) | (f2bfu(v.w)<<16);
  uint2 o; o.x = lo; o.y = hi;
  *(uint2*)(d + i) = o;
}

// ---------------------------------------------------------------------------
// FUSED gemm + gates launch. FIXED grid vs round 9:
//   blocks [0,256):    gates (16384/64 = 256 blocks) — dispatched FIRST so
//                      their cost hides under the gemm stream
//   blocks [256,3328): QKV GEMM tiles, gi = blockIdx.x-256,
//                      m0=(gi/24)*128 (128 M-tiles), n0=(gi%24)*128 (24 N-tiles)
// Disjoint data (gemm: xb/wcat->qkv; gates: fp32 x -> cm/c1/pp). 48KB LDS both.
// ---------------------------------------------------------------------------
#define SC_ 132   // Cs stride (u16); epilogue LDS-bounce
#define NGATES_ 256

__global__ __launch_bounds__(256, 3) void gemm_gates_kernel(
    const unsigned short* __restrict__ A, const unsigned short* __restrict__ Bw,
    unsigned short* __restrict__ C,
    const float* __restrict__ x,
    const float* __restrict__ mdw, const float* __restrict__ mdb,
    const float* __restrict__ sw,  const float* __restrict__ sb,
    const float* __restrict__ lw,  const float* __restrict__ lb,
    float* __restrict__ cmb, float* __restrict__ c1b, float* __restrict__ ppb)
{
  __shared__ __align__(16) unsigned short smem[24576];   // 48 KB union
  const int tid = threadIdx.x;

  if (blockIdx.x >= NGATES_){
    // ================= GEMM tile (round-7 body) =================
    const int gi = blockIdx.x - NGATES_;          // 0..3071
    const int K = HID_;
    unsigned short* As = smem;            // [3][4096]
    unsigned short* Bs = smem + 12288;    // [3][4096]

    const int lane = tid & 63, wave = tid >> 6;
    const int lq = lane & 15, quad = lane >> 4;
    const int m0 = (gi / 24) * 128, n0 = (gi % 24) * 128;
    const int row = tid >> 2, ks = (tid & 3)*8;
    const int mo = (wave & 1)*64, no = (wave >> 1)*64;

    const unsigned short* pa0 = A  + (size_t)(m0 + row)*K + ks;
    const unsigned short* pa1 = pa0 + (size_t)64*K;
    const unsigned short* pb0 = Bw + (size_t)(n0 + row)*K + ks;
    const unsigned short* pb1 = pb0 + (size_t)64*K;

    facc_t acc[4][4];
    #pragma unroll
    for (int i=0;i<4;++i)
      #pragma unroll
      for (int j=0;j<4;++j) acc[i][j] = (facc_t){0.f,0.f,0.f,0.f};

    auto stage = [&](int buf, int kt){
      const int off = kt*32;
      unsigned short* ab = As + buf*4096 + wave*512;
      unsigned short* bb = Bs + buf*4096 + wave*512;
      gld16(pa0 + off, ab);
      gld16(pa1 + off, ab + 2048);
      gld16(pb0 + off, bb);
      gld16(pb1 + off, bb + 2048);
    };

    const int kiters = K >> 5;   // 32
    stage(0, 0);
    stage(1, 1);
    asm volatile("s_waitcnt vmcnt(4)" ::: "memory");
    __builtin_amdgcn_s_barrier();
    __builtin_amdgcn_sched_barrier(0);

    int cur = 0;
    for (int kt = 0; kt < kiters; ++kt){
      if (kt+2 < kiters){
        int b2 = cur + 2; if (b2 >= 3) b2 -= 3;
        stage(b2, kt+2);
      }
      const unsigned short* as = As + cur*4096;
      const unsigned short* bs = Bs + cur*4096;
      bfrag_t af[4], bf[4];
      #pragma unroll
      for (int mt=0;mt<4;++mt) af[mt] = *(const bfrag_t*)&as[(mo+mt*16+lq)*32 + quad*8];
      #pragma unroll
      for (int nt=0;nt<4;++nt) bf[nt] = *(const bfrag_t*)&bs[(no+nt*16+lq)*32 + quad*8];
      #pragma unroll
      for (int mt=0;mt<4;++mt)
        #pragma unroll
        for (int nt=0;nt<4;++nt)
          acc[mt][nt] = MFMA16(af[mt], bf[nt], acc[mt][nt]);
      if (kt+1 < kiters){
        if (kt+2 < kiters) asm volatile("s_waitcnt vmcnt(4)" ::: "memory");
        else               asm volatile("s_waitcnt vmcnt(0)" ::: "memory");
        __builtin_amdgcn_s_barrier();
        __builtin_amdgcn_sched_barrier(0);
      }
      cur = (cur == 2) ? 0 : cur + 1;
    }

    // ---- epilogue: acc -> Cs (LDS) -> coalesced uint4 global stores ----
    __syncthreads();
    unsigned short* Cs = smem;            // [128][SC_]
    #pragma unroll
    for (int mt=0;mt<4;++mt)
      #pragma unroll
      for (int nt=0;nt<4;++nt)
        #pragma unroll
        for (int r=0;r<4;++r){
          const int lr = mo + mt*16 + quad*4 + r;
          const int lc = no + nt*16 + lq;
          Cs[lr*SC_ + lc] = (unsigned short)f2bfu(acc[mt][nt][r]);
        }
    __syncthreads();
    #pragma unroll
    for (int u=0;u<8;++u){
      const int idx = tid + 256*u;        // 0..2047
      const int ml = idx >> 4, s = idx & 15;
      const int rr = m0 + ml;
      const int cc0 = n0 + s*8;
      const int t = cc0 >> 10, hh = (cc0 >> 6) & 15, dd0 = cc0 & 63;
      const int b = rr >> 12, l = rr & 4095;
      uint2 v0 = *(const uint2*)&Cs[ml*SC_ + s*8];
      uint2 v1 = *(const uint2*)&Cs[ml*SC_ + s*8 + 4];
      uint4 v; v.x = v0.x; v.y = v0.y; v.z = v1.x; v.w = v1.y;
      *(uint4*)&C[((((size_t)t*B_ + b)*H_ + hh)*L_ + l)*64 + dd0] = v;
    }
    return;
  }

  // ================= gates block (round-7 scalar body) =================
  float (*xs)[68] = (float(*)[68])(void*)smem;             // 64x68 f32 = 17408B
  float (*wg)[68] = (float(*)[68])(void*)(smem + 8704);    // 48x68 f32 = 13056B
  const int m0 = blockIdx.x * 64;                          // 0..16320
  const int tx = tid & 15, ty = tid >> 4;
  float acc[4][3];
  #pragma unroll
  for (int r=0;r<4;++r){ acc[r][0]=0.f; acc[r][1]=0.f; acc[r][2]=0.f; }

  for (int k0 = 0; k0 < HID_; k0 += 64){
    {
      const int r = tid >> 2, kq = tid & 3;
      const float* xp = x + (size_t)(m0 + r) * HID_ + k0 + kq*16;
      #pragma unroll
      for (int u=0;u<4;++u){
        float4 v = *(const float4*)(xp + u*4);
        *(float4*)&xs[r][kq*16 + u*4] = v;
      }
    }
    #pragma unroll
    for (int u=0;u<3;++u){
      const int idx = tid + 256*u;
      const int gi = idx >> 4, q = idx & 15;
      const float* wp = (gi < 16) ? (mdw + (size_t)gi*HID_)
                      : (gi < 32) ? (sw  + (size_t)(gi-16)*HID_)
                                  : (lw  + (size_t)(gi-32)*HID_);
      float4 v = *(const float4*)(wp + k0 + q*4);
      *(float4*)&wg[gi][q*4] = v;
    }
    __syncthreads();
    for (int kk=0; kk<64; ++kk){
      float xv[4], wv[3];
      #pragma unroll
      for (int r=0;r<4;++r) xv[r] = xs[ty*4+r][kk];
      #pragma unroll
      for (int gg=0;gg<3;++gg) wv[gg] = wg[tx*3+gg][kk];
      #pragma unroll
      for (int r=0;r<4;++r)
        #pragma unroll
        for (int gg=0;gg<3;++gg) acc[r][gg] += xv[r]*wv[gg];
    }
    __syncthreads();
  }

  float (*ls)[68] = xs;
  #pragma unroll
  for (int gg=0; gg<3; ++gg){
    const int gi = tx*3 + gg;
    const int s = gi >> 4, hh = gi & 15;
    const float bias = (s==0) ? mdb[hh] : (s==1) ? sb[hh] : lb[hh];
    #pragma unroll
    for (int r=0;r<4;++r) ls[gi][ty*4+r] = acc[r][gg] + bias;
  }
  __syncthreads();

  const int lane = tid & 63, wv2 = tid >> 6;
  const int b = m0 >> 12, n = (m0 & 4095) >> 6;
  #pragma unroll
  for (int u=0;u<4;++u){
    const int hh = wv2*4 + u;
    const float md = 1.0f - sigf(ls[hh][lane]);
    const float sd = sigf(ls[16+hh][lane]);
    const float lr = sigf(ls[32+hh][lane]);
    float vm = md, vs = sd;
    #pragma unroll
    for (int off = 1; off < 64; off <<= 1){
      float om = __shfl_down(vm, off);
      float os = __shfl_down(vs, off);
      if (lane + off < 64){ vm *= om; vs *= os; }
    }
    float mex = __shfl_down(vm, 1);
    float sex = __shfl_down(vs, 1);
    if (lane == 63){ mex = 1.0f; sex = 1.0f; }
    const size_t base = ((size_t)(b*16 + hh)*NCH_ + n)*64;
    cmb[base + lane] = mex;
    c1b[base + lane] = -lr * sex;
    if (lane == 0){
      ppb[((size_t)(b*16+hh)*NCH_ + n)*2 + 0] = vm;
      ppb[((size_t)(b*16+hh)*NCH_ + n)*2 + 1] = vs;
    }
  }
}

// ---------------------------------------------------------------------------
// halo_kernel: snapshot RAW q/k/v rows (ch*64-3 .. ch*64-1) before prep
// overwrites them in place. halo layout: [tensor][bh][ch][3][64] bf16.
// ---------------------------------------------------------------------------
#define HALO_T_ ((size_t)64*64*3*64)

__global__ __launch_bounds__(192) void halo_kernel(
  const unsigned short* __restrict__ qg, const unsigned short* __restrict__ kg,
  const unsigned short* __restrict__ vg, unsigned short* __restrict__ halo)
{
  const int blk = blockIdx.x;          // 64*63 blocks
  const int bh = blk / 63;
  const int ch = blk % 63 + 1;         // 1..63
  const int tid = threadIdx.x;
  const int tt = tid >> 6, lane = tid & 63;
  const long src = ((long)bh*L_ + (long)ch*64 - 3 + tt)*64 + lane;
  const long dst = (((long)bh*64 + ch)*3 + tt)*64 + lane;
  halo[dst]               = qg[src];
  halo[dst +   HALO_T_]   = kg[src];
  halo[dst + 2*HALO_T_]   = vg[src];
}

// ---------------------------------------------------------------------------
// prep_kernel: conv+silu(+rmsnorm for q,k) IN PLACE over gemm output, plus
// kred[bh][ch][d] = sum_i cm[i]*kc_bf16[i][d]. One block per (bh, chunk).
// ---------------------------------------------------------------------------
__global__ __launch_bounds__(256) void prep_kernel(
  unsigned short* __restrict__ qg, unsigned short* __restrict__ kg,
  unsigned short* __restrict__ vg,
  const unsigned short* __restrict__ halo,
  const float* __restrict__ cmg,
  const float* __restrict__ cqw, const float* __restrict__ cqb,
  const float* __restrict__ ckw, const float* __restrict__ ckb,
  const float* __restrict__ cvw, const float* __restrict__ cvb,
  const float* __restrict__ qnw, const float* __restrict__ knw,
  float* __restrict__ kredg)
{
  const int blk = blockIdx.x;          // bh*64 + ch
  const int bh = blk >> 6, ch = blk & 63;
  const int tid = threadIdx.x;
  const int lane = tid & 63, wave = tid >> 6;
  const int h = bh & 15;
  const int c = h*64 + lane;

  float wq4[4], wk4[4], wv4[4];
  #pragma unroll
  for (int kk=0;kk<4;++kk){ wq4[kk]=cqw[c*4+kk]; wk4[kk]=ckw[c*4+kk]; wv4[kk]=cvw[c*4+kk]; }
  const float bq = cqb[c], bk = ckb[c], bv = cvb[c];
  const float qnf = qnw[lane], knf = knw[lane];

  const long base = ((long)bh*L_ + (long)ch*64)*64 + lane;
  const int r0 = wave*16;

  // ---- sliding window init (RAW values, read before any in-block write) ----
  float qw_[3], kw_[3], vw_[3];
  #pragma unroll
  for (int t=0;t<3;++t){
    const int row = r0 - 3 + t;
    if (row >= 0){
      qw_[t] = bf2f(qg[base + (long)row*64]);
      kw_[t] = bf2f(kg[base + (long)row*64]);
      vw_[t] = bf2f(vg[base + (long)row*64]);
    } else if (ch == 0){
      qw_[t] = 0.f; kw_[t] = 0.f; vw_[t] = 0.f;
    } else {
      const long hb = (((long)bh*64 + ch)*3 + (row + 3))*64 + lane;
      qw_[t] = bf2f(halo[hb]);
      kw_[t] = bf2f(halo[hb +   HALO_T_]);
      vw_[t] = bf2f(halo[hb + 2*HALO_T_]);
    }
  }
  __syncthreads();   // all cross-wave RAW reads done before any write

  const float* cmp = cmg + ((size_t)bh*NCH_ + ch)*64;
  float kp = 0.f;
  #pragma unroll 8
  for (int i=0;i<16;++i){
    const int row = r0 + i;
    const long a = base + (long)row*64;
    const float q0v = bf2f(qg[a]);
    const float k0v = bf2f(kg[a]);
    const float v0v = bf2f(vg[a]);
    float aq = bq + wq4[0]*qw_[0] + wq4[1]*qw_[1] + wq4[2]*qw_[2] + wq4[3]*q0v;
    float ak = bk + wk4[0]*kw_[0] + wk4[1]*kw_[1] + wk4[2]*kw_[2] + wk4[3]*k0v;
    float av = bv + wv4[0]*vw_[0] + wv4[1]*vw_[1] + wv4[2]*vw_[2] + wv4[3]*v0v;
    const float yk = ak*sigf(ak), yq = aq*sigf(aq), yv = av*sigf(av);
    const float ssk = wsum64(yk*yk);
    const float ssq = wsum64(yq*yq);
    const float vk = knf * yk * rsqrtf(ssk*(1.0f/64.0f) + EPS_);
    const float vq = qnf * yq * rsqrtf(ssq*(1.0f/64.0f) + EPS_);
    const unsigned short kb16 = (unsigned short)f2bfu(vk);
    qg[a] = (unsigned short)f2bfu(vq);
    kg[a] = kb16;
    vg[a] = (unsigned short)f2bfu(yv);
    kp += cmp[row] * bf2f(kb16);
    qw_[0]=qw_[1]; qw_[1]=qw_[2]; qw_[2]=q0v;
    kw_[0]=kw_[1]; kw_[1]=kw_[2]; kw_[2]=k0v;
    vw_[0]=vw_[1]; vw_[1]=vw_[2]; vw_[2]=v0v;
  }

  __shared__ float kpart[4][64];
  kpart[wave][lane] = kp;
  __syncthreads();
  if (wave == 0)
    kredg[((size_t)bh*NCH_ + ch)*64 + lane] =
        (kpart[0][lane]+kpart[1][lane]) + (kpart[2][lane]+kpart[3][lane]);
}

// ---------------------------------------------------------------------------
// MFMA chunk scan: 1024 threads (16 waves), round-2 6-barrier schedule
// (best measured: 399 us).
// ---------------------------------------------------------------------------
#define SK 72    // stride (u16) of 64-wide arrays  (36 dw == 4 mod 32)
#define SX 136   // stride (u16) of 128-wide arrays (68 dw == 4 mod 32)

__global__ __launch_bounds__(1024, 4) void scan_kernel(
  const unsigned short* __restrict__ qg, const unsigned short* __restrict__ kg,
  const unsigned short* __restrict__ vg,
  const float* __restrict__ cmg, const float* __restrict__ c1g,
  const float* __restrict__ ppg, const float* __restrict__ krg,
  const float* __restrict__ W1in, const float* __restrict__ W2in,
  float* __restrict__ out)
{
  const int bh = blockIdx.x;
  const int h = bh & 15;
  const int tid = threadIdx.x;
  const int lane = tid & 63, wave = tid >> 6;      // wave 0..15
  const int lq = lane & 15, quad = lane >> 4;
  const int wg = wave & 3;                         // row group 0..3
  const int rw = wg * 16;
  const int cw = wave >> 2;                        // col group 0..3
  const int r0 = rw + quad*4;

  // u16 offsets: kcs s: s*4608; qcs: 9216+s*4608; gms: 18432+s*4608;
  // xbs: 27648; W1T: 36352; W2n: 45568; W2T: 54784; end 63488 (127 KB)
  __shared__ __align__(16) unsigned short sm[63488];
  unsigned short* xbs = sm + 27648;   // [64][SX]
  unsigned short* W1T = sm + 36352;   // [128][SK]  W1^T (k=d contiguous)
  unsigned short* W2n = sm + 45568;   // [128][SK]  W2 [j][e]
  unsigned short* W2T = sm + 54784;   // [64][SX]   W2^T [e][j]
  __shared__ float cmA[2][64], c1A[2][64], krA[2][64], ppS[2][2];
  __shared__ float kmomS[64], xmomS[128], w1momS[128], w2momS[64];
  __shared__ float xpart[4][128], w1part[4][128], w2part[4][64];

  // ---- init state: each thread one 8-elem strip ----
  {
    const int j = tid >> 3, q0 = (tid & 7) * 8;
    const float* w1p = W1in + (size_t)h * D_ * DM_;
    #pragma unroll
    for (int t=0;t<8;++t)
      W1T[j*SK + q0 + t] = (unsigned short)f2bfu(w1p[(size_t)(q0+t)*DM_ + j]);
    const float* w2p = W2in + (size_t)h * DM_ * D_ + (size_t)j*D_ + q0;
    #pragma unroll
    for (int t=0;t<8;++t){
      unsigned short v = (unsigned short)f2bfu(w2p[t]);
      W2n[j*SK + q0 + t] = v;
      W2T[(q0+t)*SX + j] = v;
    }
  }
  if (tid < 64){ kmomS[tid]=0.f; w2momS[tid]=0.f; }
  if (tid < 128){ xmomS[tid]=0.f; w1momS[tid]=0.f; }

  const long cbase = (long)bh * L_ * 64;   // head-major
  const int tr = tid >> 4, tc = (tid & 15) * 4;   // 64 rows x 64 cols, uint2

  uint2 rq2, rk2, rv2;
  float cmr=0.f, c1r=0.f, krr=0.f, ppr=0.f;

  auto stage_load = [&](int m){
    if (m >= NCH_) return;
    const long a = cbase + ((long)m*64 + tr)*64 + tc;
    rq2 = *(const uint2*)(qg + a);
    rk2 = *(const uint2*)(kg + a);
    rv2 = *(const uint2*)(vg + a);
    if (wave == 0){
      cmr = cmg[((size_t)bh*NCH_ + m)*64 + lane];
      c1r = c1g[((size_t)bh*NCH_ + m)*64 + lane];
      krr = krg[((size_t)bh*NCH_ + m)*64 + lane];
    }
    if (tid < 2) ppr = ppg[((size_t)bh*NCH_ + m)*2 + tid];
  };

  auto stage_store = [&](int m, int s){
    if (m >= NCH_) return;
    unsigned short* kc = sm + s*4608;
    unsigned short* qc = sm + 9216 + s*4608;
    unsigned short* gm = sm + 18432 + s*4608;
    *(uint2*)&kc[tr*SK + tc] = rk2;
    *(uint2*)&qc[tr*SK + tc] = rq2;
    *(uint2*)&gm[tr*SK + tc] = rv2;
    if (wave == 0){ cmA[s][lane] = cmr; c1A[s][lane] = c1r; krA[s][lane] = krr; }
    if (tid < 2) ppS[s][tid] = ppr;
  };

  stage_load(0);
  stage_store(0, 0);
  __syncthreads();

  for (int n = 0; n < NCH_; ++n){
    const int cur = n & 1, nxt = cur ^ 1;
    const unsigned short* kcs = sm + cur*4608;
    const unsigned short* qcs = sm + 9216 + cur*4608;
    unsigned short* gms = sm + 18432 + cur*4608;

    stage_load(n+1);   // global loads issue here; latency hides under P2/P4

    // ---- P2: Z1 = kc @ W1 ; X1 = silu(Z1) -> xbs ; xmom partials ----
    facc_t zk[2];
    {
      const bfrag_t a0 = *(const bfrag_t*)&kcs[(rw+lq)*SK + quad*8];
      const bfrag_t a1 = *(const bfrag_t*)&kcs[(rw+lq)*SK + 32 + quad*8];
      const float4 cmv = *(const float4*)&cmA[cur][r0];
      #pragma unroll
      for (int nt=0;nt<2;++nt){
        const int j = cw*32 + nt*16 + lq;
        const bfrag_t b0 = *(const bfrag_t*)&W1T[j*SK + quad*8];
        const bfrag_t b1 = *(const bfrag_t*)&W1T[j*SK + 32 + quad*8];
        facc_t z = {0.f,0.f,0.f,0.f};
        z = MFMA16(a0,b0,z); z = MFMA16(a1,b1,z);
        zk[nt] = z;
        const float x0 = z[0]*sigf(z[0]), x1 = z[1]*sigf(z[1]);
        const float x2 = z[2]*sigf(z[2]), x3 = z[3]*sigf(z[3]);
        const unsigned p01 = cvtpk(x0,x1), p23 = cvtpk(x2,x3);
        xbs[(r0+0)*SX + j] = (unsigned short)p01;
        xbs[(r0+1)*SX + j] = (unsigned short)(p01>>16);
        xbs[(r0+2)*SX + j] = (unsigned short)p23;
        xbs[(r0+3)*SX + j] = (unsigned short)(p23>>16);
        float xp = cmv.x*x0 + cmv.y*x1 + cmv.z*x2 + cmv.w*x3;
        xp += __shfl_xor(xp, 16);
        xp += __shfl_xor(xp, 32);
        if (quad == 0) xpart[wg][j] = xp;
      }
    }
    __syncthreads();   // b1

    // ---- P4: g_m = X1 @ W2 - v ; w2mom partial ; kmom/xmom finalize ----
    {
      bfrag_t xa[4];
      #pragma unroll
      for (int kt=0;kt<4;++kt) xa[kt] = *(const bfrag_t*)&xbs[(rw+lq)*SX + kt*32 + quad*8];
      const int e = cw*16 + lq;
      facc_t z = {0.f,0.f,0.f,0.f};
      #pragma unroll
      for (int kt=0;kt<4;++kt){
        const bfrag_t bb = *(const bfrag_t*)&W2T[e*SX + kt*32 + quad*8];
        z = MFMA16(xa[kt], bb, z);
      }
      const float g0 = z[0] - bf2f(gms[(r0+0)*SK + e]);
      const float g1 = z[1] - bf2f(gms[(r0+1)*SK + e]);
      const float g2 = z[2] - bf2f(gms[(r0+2)*SK + e]);
      const float g3 = z[3] - bf2f(gms[(r0+3)*SK + e]);
      const unsigned p01 = cvtpk(g0,g1), p23 = cvtpk(g2,g3);
      gms[(r0+0)*SK + e] = (unsigned short)p01;
      gms[(r0+1)*SK + e] = (unsigned short)(p01>>16);
      gms[(r0+2)*SK + e] = (unsigned short)p23;
      gms[(r0+3)*SK + e] = (unsigned short)(p23>>16);
      const float4 c1v = *(const float4*)&c1A[cur][r0];
      float wp = c1v.x*g0 + c1v.y*g1 + c1v.z*g2 + c1v.w*g3;
      wp += __shfl_xor(wp, 16);
      wp += __shfl_xor(wp, 32);
      if (quad == 0) w2part[wg][e] = wp;
    }
    if (tid < 64) kmomS[tid] = ppS[cur][0]*kmomS[tid] + krA[cur][tid];
    if (tid < 128)
      xmomS[tid] = ppS[cur][0]*xmomS[tid]
                 + ((xpart[0][tid]+xpart[1][tid])+(xpart[2][tid]+xpart[3][tid]));
    stage_store(n+1, nxt);
    __syncthreads();   // b2

    // ---- P5: gZ1 -> xbs ; w1mom partial ; w2mom finalize ----
    {
      const bfrag_t a0 = *(const bfrag_t*)&gms[(rw+lq)*SK + quad*8];
      const bfrag_t a1 = *(const bfrag_t*)&gms[(rw+lq)*SK + 32 + quad*8];
      const float4 c1v = *(const float4*)&c1A[cur][r0];
      #pragma unroll
      for (int nt=0;nt<2;++nt){
        const int j = cw*32 + nt*16 + lq;
        const bfrag_t b0 = *(const bfrag_t*)&W2n[j*SK + quad*8];
        const bfrag_t b1 = *(const bfrag_t*)&W2n[j*SK + 32 + quad*8];
        facc_t gz = {0.f,0.f,0.f,0.f};
        gz = MFMA16(a0,b0,gz); gz = MFMA16(a1,b1,gz);
        float d[4];
        #pragma unroll
        for (int r=0;r<4;++r){
          const float zz = zk[nt][r];
          const float sg = sigf(zz);
          d[r] = gz[r] * (sg * (1.0f + zz*(1.0f - sg)));
        }
        const unsigned p01 = cvtpk(d[0],d[1]), p23 = cvtpk(d[2],d[3]);
        xbs[(r0+0)*SX + j] = (unsigned short)p01;
        xbs[(r0+1)*SX + j] = (unsigned short)(p01>>16);
        xbs[(r0+2)*SX + j] = (unsigned short)p23;
        xbs[(r0+3)*SX + j] = (unsigned short)(p23>>16);
        float wp = c1v.x*d[0] + c1v.y*d[1] + c1v.z*d[2] + c1v.w*d[3];
        wp += __shfl_xor(wp, 16);
        wp += __shfl_xor(wp, 32);
        if (quad == 0) w1part[wg][j] = wp;
      }
    }
    if (tid < 64)
      w2momS[tid] = ppS[cur][1]*w2momS[tid]
                  + ((w2part[0][tid]+w2part[1][tid])+(w2part[2][tid]+w2part[3][tid]));
    __syncthreads();   // b3

    // ---- P7: w1mom finalize (inline, same-wave lockstep) + rank-1 updates ----
    {
      const float Pmd = ppS[cur][0], Psd = ppS[cur][1];
      const int j = tid >> 3, q0 = (tid & 7)*8;
      const float w1m = Psd*w1momS[j]
          + ((w1part[0][j]+w1part[1][j])+(w1part[2][j]+w1part[3][j]));
      if ((tid & 7) == 0) w1momS[j] = w1m;   // 8 threads/j share one wave
      const float xm = xmomS[j];
      const float4 km0 = *(const float4*)&kmomS[q0];
      const float4 km1 = *(const float4*)&kmomS[q0+4];
      {
        const int off = j*SK + q0;
        const uint4 w = *(const uint4*)&W1T[off];
        uint4 o;
        o.x = cvtpk(Pmd*bflo(w.x) + w1m*km0.x, Pmd*bfhi(w.x) + w1m*km0.y);
        o.y = cvtpk(Pmd*bflo(w.y) + w1m*km0.z, Pmd*bfhi(w.y) + w1m*km0.w);
        o.z = cvtpk(Pmd*bflo(w.z) + w1m*km1.x, Pmd*bfhi(w.z) + w1m*km1.y);
        o.w = cvtpk(Pmd*bflo(w.w) + w1m*km1.z, Pmd*bfhi(w.w) + w1m*km1.w);
        *(uint4*)&W1T[off] = o;
      }
      const float4 wm0 = *(const float4*)&w2momS[q0];
      const float4 wm1 = *(const float4*)&w2momS[q0+4];
      {
        const int off = j*SK + q0;
        const uint4 w = *(const uint4*)&W2n[off];
        uint4 o;
        o.x = cvtpk(Pmd*bflo(w.x) + xm*wm0.x, Pmd*bfhi(w.x) + xm*wm0.y);
        o.y = cvtpk(Pmd*bflo(w.y) + xm*wm0.z, Pmd*bfhi(w.y) + xm*wm0.w);
        o.z = cvtpk(Pmd*bflo(w.z) + xm*wm1.x, Pmd*bfhi(w.z) + xm*wm1.y);
        o.w = cvtpk(Pmd*bflo(w.w) + xm*wm1.z, Pmd*bfhi(w.w) + xm*wm1.w);
        *(uint4*)&W2n[off] = o;
      }
      const int e2 = tid >> 4, js = (tid & 15)*8;
      const float w2m = w2momS[e2];
      const float4 xm0 = *(const float4*)&xmomS[js];
      const float4 xm1 = *(const float4*)&xmomS[js+4];
      {
        const int off = e2*SX + js;
        const uint4 w = *(const uint4*)&W2T[off];
        uint4 o;
        o.x = cvtpk(Pmd*bflo(w.x) + xm0.x*w2m, Pmd*bfhi(w.x) + xm0.y*w2m);
        o.y = cvtpk(Pmd*bflo(w.y) + xm0.z*w2m, Pmd*bfhi(w.y) + xm0.w*w2m);
        o.z = cvtpk(Pmd*bflo(w.z) + xm1.x*w2m, Pmd*bfhi(w.z) + xm1.y*w2m);
        o.w = cvtpk(Pmd*bflo(w.w) + xm1.z*w2m, Pmd*bfhi(w.w) + xm1.w*w2m);
        *(uint4*)&W2T[off] = o;
      }
    }
    __syncthreads();   // b4

    // ---- P8: hq = silu(qc @ W1new) -> xbs ----
    {
      const bfrag_t a0 = *(const bfrag_t*)&qcs[(rw+lq)*SK + quad*8];
      const bfrag_t a1 = *(const bfrag_t*)&qcs[(rw+lq)*SK + 32 + quad*8];
      #pragma unroll
      for (int nt=0;nt<2;++nt){
        const int j = cw*32 + nt*16 + lq;
        const bfrag_t b0 = *(const bfrag_t*)&W1T[j*SK + quad*8];
        const bfrag_t b1 = *(const bfrag_t*)&W1T[j*SK + 32 + quad*8];
        facc_t z = {0.f,0.f,0.f,0.f};
        z = MFMA16(a0,b0,z); z = MFMA16(a1,b1,z);
        const float x0 = z[0]*sigf(z[0]), x1 = z[1]*sigf(z[1]);
        const float x2 = z[2]*sigf(z[2]), x3 = z[3]*sigf(z[3]);
        const unsigned p01 = cvtpk(x0,x1), p23 = cvtpk(x2,x3);
        xbs[(r0+0)*SX + j] = (unsigned short)p01;
        xbs[(r0+1)*SX + j] = (unsigned short)(p01>>16);
        xbs[(r0+2)*SX + j] = (unsigned short)p23;
        xbs[(r0+3)*SX + j] = (unsigned short)(p23>>16);
      }
    }
    __syncthreads();   // b5

    // ---- P9: y = hq @ W2new -> out (B,H,D,L flat) ----
    {
      bfrag_t xa[4];
      #pragma unroll
      for (int kt=0;kt<4;++kt) xa[kt] = *(const bfrag_t*)&xbs[(rw+lq)*SX + kt*32 + quad*8];
      const int e = cw*16 + lq;
      facc_t y = {0.f,0.f,0.f,0.f};
      #pragma unroll
      for (int kt=0;kt<4;++kt){
        const bfrag_t bb = *(const bfrag_t*)&W2T[e*SX + kt*32 + quad*8];
        y = MFMA16(xa[kt], bb, y);
      }
      float4 ov; ov.x = y[0]; ov.y = y[1]; ov.z = y[2]; ov.w = y[3];
      *(float4*)&out[(size_t)bh*D_*L_ + (size_t)e*L_ + n*64 + rw + quad*4] = ov;
    }
    __syncthreads();   // b6
  }
}

extern "C" void kernel_launch(void* const* d_in, const int* in_sizes, int n_in,
                              void* d_out, int out_size, void* d_ws, size_t ws_size,
                              hipStream_t stream)
{
  const float* x   = (const float*)d_in[0];
  const float* Wq  = (const float*)d_in[1];
  const float* Wk  = (const float*)d_in[2];
  const float* Wv  = (const float*)d_in[3];
  const float* cqw = (const float*)d_in[4];
  const float* cqb = (const float*)d_in[5];
  const float* ckw = (const float*)d_in[6];
  const float* ckb = (const float*)d_in[7];
  const float* cvw = (const float*)d_in[8];
  const float* cvb = (const float*)d_in[9];
  const float* qnw = (const float*)d_in[10];
  const float* knw = (const float*)d_in[11];
  const float* mdw = (const float*)d_in[12];
  const float* mdb = (const float*)d_in[13];
  const float* sw  = (const float*)d_in[14];
  const float* sb  = (const float*)d_in[15];
  const float* lw  = (const float*)d_in[16];
  const float* lb  = (const float*)d_in[17];
  const float* W1  = (const float*)d_in[18];
  const float* W2  = (const float*)d_in[19];
  float* out = (float*)d_out;

  const size_t SZ  = (size_t)B_ * L_ * HID_;   // 16,777,216
  const size_t WSZ = (size_t)HID_ * HID_;      //  1,048,576
  unsigned short* xb  = (unsigned short*)d_ws;
  unsigned short* wqb = xb  + SZ;      // wq/wk/wv contiguous = Wcat[3072][1024]
  unsigned short* wkb = wqb + WSZ;
  unsigned short* wvb = wkb + WSZ;
  unsigned short* qb  = wvb + WSZ;     // q/k/v contiguous, head-major each
  unsigned short* kb  = qb  + SZ;
  unsigned short* vb  = kb  + SZ;
  float* cmb = (float*)(vb + SZ);
  float* c1b = cmb + (size_t)B_*H_*NCH_*64;
  float* ppb = c1b + (size_t)B_*H_*NCH_*64;
  float* kredg = ppb + (size_t)B_*H_*NCH_*2;
  unsigned short* halo = (unsigned short*)(kredg + (size_t)B_*H_*NCH_*64);

  cast_kernel<<<16384 + 3*1024, 256, 0, stream>>>(x, Wq, Wk, Wv, xb, wqb, wkb, wvb);
  // fused: 256 gates blocks first (hide under gemm), then 3072 gemm tiles
  gemm_gates_kernel<<<NGATES_ + 3072, 256, 0, stream>>>(
      xb, wqb, qb, x, mdw, mdb, sw, sb, lw, lb, cmb, c1b, ppb);
  halo_kernel<<<64*63, 192, 0, stream>>>(qb, kb, vb, halo);
  prep_kernel<<<B_*H_*NCH_, 256, 0, stream>>>(qb, kb, vb, halo, cmb,
                                              cqw, cqb, ckw, ckb, cvw, cvb,
                                              qnw, knw, kredg);
  scan_kernel<<<B_*H_, 1024, 0, stream>>>(qb, kb, vb, cmb, c1b, ppb, kredg,
                                          W1, W2, out);
}